// Round 2
// baseline (2556.201 us; speedup 1.0000x reference)
//
#include <hip/hip_runtime.h>

#define NN_ 8192
#define MM_ 1024

// ============================ FPS =============================
// One block per batch. 512 threads own 16 points each (p = j*512 + tid).
// Exact-fp32 replication of the reference: rn ops, first-index argmax ties.
__global__ __launch_bounds__(512) void fps_kernel(const float* __restrict__ xyz,
                                                  float* __restrict__ dout) {
  const int b = blockIdx.x;
  const int tid = threadIdx.x;
  const float* xb = xyz + (size_t)b * NN_ * 3;

  float px[16], py[16], pz[16], pd[16];
#pragma unroll
  for (int j = 0; j < 16; ++j) {
    const int p = j * 512 + tid;
    px[j] = xb[p * 3 + 0];
    py[j] = xb[p * 3 + 1];
    pz[j] = xb[p * 3 + 2];
    pd[j] = 1e10f;
  }

  __shared__ float s_cent[3];
  __shared__ float s_rd[8];
  __shared__ int s_rp[8];

  if (tid == 0) { s_cent[0] = xb[0]; s_cent[1] = xb[1]; s_cent[2] = xb[2]; }
  __syncthreads();

  const int lane = tid & 63;
  const int wv = tid >> 6;
  float* outx = dout + (size_t)b * MM_ * 3;

  for (int it = 0; it < MM_; ++it) {
    const float cx = s_cent[0], cy = s_cent[1], cz = s_cent[2];
    if (tid == 0) {
      outx[it * 3 + 0] = cx;
      outx[it * 3 + 1] = cy;
      outx[it * 3 + 2] = cz;
    }
    if (it == MM_ - 1) break;

    // distance update + local argmax (strict > keeps smallest p on ties)
    float ld = -1.0f;
    int lj = 0;
#pragma unroll
    for (int j = 0; j < 16; ++j) {
      const float dx = __fsub_rn(px[j], cx);
      const float dy = __fsub_rn(py[j], cy);
      const float dz = __fsub_rn(pz[j], cz);
      const float dist = __fadd_rn(__fadd_rn(__fmul_rn(dx, dx), __fmul_rn(dy, dy)),
                                   __fmul_rn(dz, dz));
      const float nd = fminf(pd[j], dist);
      pd[j] = nd;
      if (nd > ld) { ld = nd; lj = j; }
    }
    int lp = lj * 512 + tid;
    // wave butterfly argmax, tie -> smaller p
#pragma unroll
    for (int mk = 1; mk < 64; mk <<= 1) {
      const float od = __shfl_xor(ld, mk, 64);
      const int op = __shfl_xor(lp, mk, 64);
      const bool take = (od > ld) || (od == ld && op < lp);
      ld = take ? od : ld;
      lp = take ? op : lp;
    }
    if (lane == 0) { s_rd[wv] = ld; s_rp[wv] = lp; }
    __syncthreads();
    // every wave redundantly reduces the 8 per-wave winners
    float rd2 = (lane < 8) ? s_rd[lane] : -1.0f;
    int rp2 = (lane < 8) ? s_rp[lane] : 0x7fffffff;
#pragma unroll
    for (int mk = 1; mk < 8; mk <<= 1) {
      const float od = __shfl_xor(rd2, mk, 64);
      const int op = __shfl_xor(rp2, mk, 64);
      const bool take = (od > rd2) || (od == rd2 && op < rp2);
      rd2 = take ? od : rd2;
      rp2 = take ? op : rp2;
    }
    const int win = __shfl(rp2, 0, 64);
    // owner thread publishes the new centroid coords (exact copies)
    if ((win & 511) == tid) {
      const int j = win >> 9;
      float wx = px[0], wy = py[0], wz = pz[0];
#pragma unroll
      for (int j2 = 1; j2 < 16; ++j2) {
        if (j2 == j) { wx = px[j2]; wy = py[j2]; wz = pz[j2]; }
      }
      s_cent[0] = wx; s_cent[1] = wy; s_cent[2] = wz;
    }
    __syncthreads();
  }
}

// ============================ KNN =============================
// One wave (block of 64) per center. Each lane owns 128 points (p = jj*64+lane).
// Distances in LDS columns + 16 group-minima in regs; 32 extraction rounds of
// lexicographic (d, p) min — reproduces top_k's set with stable tie-break.
// Dot product uses an FMA chain (matches einsum/gemm inner-loop contraction);
// squared norms stay non-FMA sequential (matches elementwise-square+reduce).
__global__ __launch_bounds__(64) void knn_kernel(const float* __restrict__ xyz,
                                                 const float* __restrict__ dout,
                                                 int* __restrict__ knn) {
  __shared__ float dl[128][64];
  const int lane = threadIdx.x;
  const int center = blockIdx.x;
  const int b = center >> 10;
  const int m = center & 1023;
  const float* xb = xyz + (size_t)b * NN_ * 3;
  const float* cp = dout + (size_t)b * MM_ * 3 + m * 3;
  const float cx = cp[0], cy = cp[1], cz = cp[2];
  const float sm = __fadd_rn(__fadd_rn(__fmul_rn(cx, cx), __fmul_rn(cy, cy)),
                             __fmul_rn(cz, cz));

  float gd[16];
  int gj[16];
#pragma unroll
  for (int g = 0; g < 16; ++g) {
#pragma unroll
    for (int t = 0; t < 8; ++t) {
      const int jj = g * 8 + t;
      const int p = jj * 64 + lane;
      const float x = xb[p * 3 + 0];
      const float y = xb[p * 3 + 1];
      const float z = xb[p * 3 + 2];
      const float sn = __fadd_rn(__fadd_rn(__fmul_rn(x, x), __fmul_rn(y, y)),
                                 __fmul_rn(z, z));
      // FMA-chained contraction: fma(z,Z, fma(y,Y, x*X))
      const float dt = __fmaf_rn(cz, z, __fmaf_rn(cy, y, __fmul_rn(cx, x)));
      const float d = __fsub_rn(__fadd_rn(sm, sn), __fmul_rn(2.0f, dt));
      dl[jj][lane] = d;
      if (t == 0) { gd[g] = d; gj[g] = jj; }
      else if (d < gd[g]) { gd[g] = d; gj[g] = jj; }
    }
  }

  int out_p = 0;
  const float INF = __int_as_float(0x7f800000);
  for (int r = 0; r < 32; ++r) {
    // local best among 16 group minima (strict < keeps smallest jj)
    float ldv = gd[0];
    int ljj = gj[0];
#pragma unroll
    for (int g = 1; g < 16; ++g) {
      if (gd[g] < ldv) { ldv = gd[g]; ljj = gj[g]; }
    }
    int lp = ljj * 64 + lane;
#pragma unroll
    for (int mk = 1; mk < 64; mk <<= 1) {
      const float od = __shfl_xor(ldv, mk, 64);
      const int op = __shfl_xor(lp, mk, 64);
      const bool take = (od < ldv) || (od == ldv && op < lp);
      ldv = take ? od : ldv;
      lp = take ? op : lp;
    }
    if (lane == r) out_p = lp;
    // winner lane marks extracted slot and rebuilds that group's min
    const int wl = lp & 63;
    if (lane == wl) {
      const int jjs = lp >> 6;
      const int gs = jjs >> 3;
      dl[jjs][lane] = INF;
      float md = INF;
      int mj = 0;
#pragma unroll
      for (int t = 0; t < 8; ++t) {
        const int jj2 = gs * 8 + t;
        const float v = dl[jj2][lane];
        if (v < md) { md = v; mj = jj2; }
      }
#pragma unroll
      for (int g = 0; g < 16; ++g) {
        if (g == gs) { gd[g] = md; gj[g] = mj; }
      }
    }
  }
  if (lane < 32) knn[center * 32 + lane] = out_p;
}

// ======================= weight transpose =====================
__global__ void prep_kernel(const float* __restrict__ w1, const float* __restrict__ w2,
                            float* __restrict__ w1t, float* __restrict__ w2t) {
  const int t = blockIdx.x * 256 + threadIdx.x;
  if (t < 4096) { const int o = t >> 6, c = t & 63; w1t[c * 64 + o] = w1[t]; }
  if (t < 8192) { const int o = t >> 6, c = t & 63; w2t[c * 128 + o] = w2[t]; }
}

// ===================== layer-1 stats pass =====================
__global__ __launch_bounds__(256) void s1_kernel(const float* __restrict__ xyz,
                                                 const float* __restrict__ dout,
                                                 const int* __restrict__ knn,
                                                 const float* __restrict__ w0,
                                                 const float* __restrict__ b0,
                                                 float* __restrict__ part1) {
  const int tid = threadIdx.x;
  const int r = blockIdx.x * 256 + tid;
  const int cid = r >> 5;
  const int b = cid >> 10;
  const int m = cid & 1023;
  const int idx = knn[r];
  const float* pp = xyz + ((size_t)b * NN_ + idx) * 3;
  const float* cc = dout + ((size_t)b * MM_ + m) * 3;
  const float fx = pp[0] - cc[0];
  const float fy = pp[1] - cc[1];
  const float fz = pp[2] - cc[2];
  float acc[64];
#pragma unroll
  for (int o = 0; o < 64; ++o)
    acc[o] = fmaf(w0[o * 3 + 2], fz, fmaf(w0[o * 3 + 1], fy, fmaf(w0[o * 3 + 0], fx, b0[o])));
  const int lane = tid & 63;
  float* po = part1 + ((size_t)blockIdx.x * 4 + (tid >> 6)) * 128;
#pragma unroll
  for (int o = 0; o < 64; ++o) {
    float s = acc[o];
    float q = acc[o] * acc[o];
#pragma unroll
    for (int mk = 1; mk < 64; mk <<= 1) { s += __shfl_xor(s, mk, 64); q += __shfl_xor(q, mk, 64); }
    if (lane == 0) { po[o] = s; po[64 + o] = q; }
  }
}

// ============ BN-fold reduce: partials -> scale/shift ==========
__global__ __launch_bounds__(256) void rstat_kernel(const float* __restrict__ part, int C,
                                                    const float* __restrict__ g,
                                                    const float* __restrict__ be,
                                                    float* __restrict__ sc,
                                                    float* __restrict__ sh) {
  const int c = blockIdx.x;
  const int tid = threadIdx.x;
  float S = 0.0f, Q = 0.0f;
  for (int i = tid; i < 4096; i += 256) {
    S += part[(size_t)i * 2 * C + c];
    Q += part[(size_t)i * 2 * C + C + c];
  }
  const int lane = tid & 63;
#pragma unroll
  for (int mk = 1; mk < 64; mk <<= 1) { S += __shfl_xor(S, mk, 64); Q += __shfl_xor(Q, mk, 64); }
  __shared__ float rs[4], rq[4];
  if (lane == 0) { rs[tid >> 6] = S; rq[tid >> 6] = Q; }
  __syncthreads();
  if (tid == 0) {
    S = rs[0] + rs[1] + rs[2] + rs[3];
    Q = rq[0] + rq[1] + rq[2] + rq[3];
    const float mean = S * (1.0f / 262144.0f);
    const float var = fmaf(-mean, mean, Q * (1.0f / 262144.0f));
    const float s = g[c] * rsqrtf(var + 1e-5f);
    sc[c] = s;
    sh[c] = fmaf(-mean, s, be[c]);
  }
}

// ============ recompute chain: STAGE 2 = stats2, 3 = stats3, 4 = final ============
template <int STAGE>
__global__ __launch_bounds__(256) void chain_kernel(
    const float* __restrict__ xyz, const float* __restrict__ dout,
    const int* __restrict__ knn,
    const float* __restrict__ w0, const float* __restrict__ b0,
    const float* __restrict__ w1t, const float* __restrict__ b1,
    const float* __restrict__ w2t, const float* __restrict__ b2,
    const float* __restrict__ sc1, const float* __restrict__ sh1,
    const float* __restrict__ sc2, const float* __restrict__ sh2,
    const float* __restrict__ sc3, const float* __restrict__ sh3,
    float* __restrict__ part, float* __restrict__ outp) {
  __shared__ float f[64 * 256];  // activations, column layout [c][tid]
  const int tid = threadIdx.x;
  const int r = blockIdx.x * 256 + tid;
  const int cid = r >> 5;
  const int b = cid >> 10;
  const int m = cid & 1023;
  const int idx = knn[r];
  const float* pp = xyz + ((size_t)b * NN_ + idx) * 3;
  const float* cc = dout + ((size_t)b * MM_ + m) * 3;
  const float fx = pp[0] - cc[0];
  const float fy = pp[1] - cc[1];
  const float fz = pp[2] - cc[2];
  float acc[64];
#pragma unroll
  for (int o = 0; o < 64; ++o)
    acc[o] = fmaf(w0[o * 3 + 2], fz, fmaf(w0[o * 3 + 1], fy, fmaf(w0[o * 3 + 0], fx, b0[o])));
  // BN1 + ReLU -> LDS (own column only; no barrier needed)
#pragma unroll
  for (int o = 0; o < 64; ++o)
    f[o * 256 + tid] = fmaxf(fmaf(acc[o], sc1[o], sh1[o]), 0.0f);
  // conv2 (output-stationary, uniform weight loads)
  float a2[64];
#pragma unroll
  for (int o = 0; o < 64; ++o) a2[o] = b1[o];
#pragma unroll 4
  for (int c = 0; c < 64; ++c) {
    const float x = f[c * 256 + tid];
#pragma unroll
    for (int o = 0; o < 64; ++o) a2[o] = fmaf(w1t[c * 64 + o], x, a2[o]);
  }
  const int lane = tid & 63;
  if constexpr (STAGE == 2) {
    float* po = part + ((size_t)blockIdx.x * 4 + (tid >> 6)) * 128;
#pragma unroll
    for (int o = 0; o < 64; ++o) {
      float s = a2[o], q = a2[o] * a2[o];
#pragma unroll
      for (int mk = 1; mk < 64; mk <<= 1) { s += __shfl_xor(s, mk, 64); q += __shfl_xor(q, mk, 64); }
      if (lane == 0) { po[o] = s; po[64 + o] = q; }
    }
    return;
  }
  // BN2 + ReLU -> LDS (overwrite own column)
#pragma unroll
  for (int o = 0; o < 64; ++o)
    f[o * 256 + tid] = fmaxf(fmaf(a2[o], sc2[o], sh2[o]), 0.0f);
#pragma unroll
  for (int h = 0; h < 2; ++h) {
    float a3[64];
#pragma unroll
    for (int o = 0; o < 64; ++o) a3[o] = b2[h * 64 + o];
#pragma unroll 4
    for (int c = 0; c < 64; ++c) {
      const float x = f[c * 256 + tid];
#pragma unroll
      for (int o = 0; o < 64; ++o) a3[o] = fmaf(w2t[c * 128 + h * 64 + o], x, a3[o]);
    }
    if constexpr (STAGE == 3) {
      float* po = part + ((size_t)blockIdx.x * 4 + (tid >> 6)) * 256;
#pragma unroll
      for (int o = 0; o < 64; ++o) {
        float s = a3[o], q = a3[o] * a3[o];
#pragma unroll
        for (int mk = 1; mk < 64; mk <<= 1) { s += __shfl_xor(s, mk, 64); q += __shfl_xor(q, mk, 64); }
        if (lane == 0) { po[h * 64 + o] = s; po[128 + h * 64 + o] = q; }
      }
    } else {
      // BN3 + ReLU + max over k (32 lanes) + transposed store
#pragma unroll
      for (int o = 0; o < 64; ++o) {
        float v = fmaxf(fmaf(a3[o], sc3[h * 64 + o], sh3[h * 64 + o]), 0.0f);
#pragma unroll
        for (int mk = 1; mk < 32; mk <<= 1) v = fmaxf(v, __shfl_xor(v, mk, 64));
        if ((lane & 31) == 0)
          outp[24576 + (size_t)b * 131072 + (size_t)(h * 64 + o) * 1024 + m] = v;
      }
    }
  }
}

// ============================ launch =============================
extern "C" void kernel_launch(void* const* d_in, const int* in_sizes, int n_in,
                              void* d_out, int out_size, void* d_ws, size_t ws_size,
                              hipStream_t stream) {
  const float* xyz = (const float*)d_in[0];
  const float* w0 = (const float*)d_in[1];
  const float* b0 = (const float*)d_in[2];
  const float* g0 = (const float*)d_in[3];
  const float* be0 = (const float*)d_in[4];
  const float* w1 = (const float*)d_in[5];
  const float* b1 = (const float*)d_in[6];
  const float* g1 = (const float*)d_in[7];
  const float* be1 = (const float*)d_in[8];
  const float* w2 = (const float*)d_in[9];
  const float* b2 = (const float*)d_in[10];
  const float* g2 = (const float*)d_in[11];
  const float* be2 = (const float*)d_in[12];
  float* out = (float*)d_out;
  char* ws = (char*)d_ws;

  // ws layout (~9.5 MB total):
  int* knn = (int*)ws;                                   // [8192][32] ints
  float* part1 = (float*)(ws + (size_t)1 * (1 << 20));   // [4096][128]
  float* part2 = (float*)(ws + (size_t)3 * (1 << 20));   // [4096][128]
  float* part3 = (float*)(ws + (size_t)5 * (1 << 20));   // [4096][256]
  float* sc1 = (float*)(ws + (size_t)9 * (1 << 20));
  float* sh1 = sc1 + 64;
  float* sc2 = sh1 + 64;
  float* sh2 = sc2 + 64;
  float* sc3 = sh2 + 64;
  float* sh3 = sc3 + 128;
  float* w1t = sh3 + 128;
  float* w2t = w1t + 4096;

  fps_kernel<<<8, 512, 0, stream>>>(xyz, out);
  knn_kernel<<<8192, 64, 0, stream>>>(xyz, out, knn);
  prep_kernel<<<32, 256, 0, stream>>>(w1, w2, w1t, w2t);
  s1_kernel<<<1024, 256, 0, stream>>>(xyz, out, knn, w0, b0, part1);
  rstat_kernel<<<64, 256, 0, stream>>>(part1, 64, g0, be0, sc1, sh1);
  chain_kernel<2><<<1024, 256, 0, stream>>>(xyz, out, knn, w0, b0, w1t, b1, w2t, b2,
                                            sc1, sh1, sc2, sh2, sc3, sh3, part2, out);
  rstat_kernel<<<64, 256, 0, stream>>>(part2, 64, g1, be1, sc2, sh2);
  chain_kernel<3><<<1024, 256, 0, stream>>>(xyz, out, knn, w0, b0, w1t, b1, w2t, b2,
                                            sc1, sh1, sc2, sh2, sc3, sh3, part3, out);
  rstat_kernel<<<128, 256, 0, stream>>>(part3, 128, g2, be2, sc3, sh3);
  chain_kernel<4><<<1024, 256, 0, stream>>>(xyz, out, knn, w0, b0, w1t, b1, w2t, b2,
                                            sc1, sh1, sc2, sh2, sc3, sh3, part3, out);
}

// Round 3
// 2001.772 us; speedup vs baseline: 1.2770x; 1.2770x over previous
//
#include <hip/hip_runtime.h>

#define NN_ 8192
#define MM_ 1024

// ============================ FPS =============================
// One block per batch, 256 threads x 32 points each (p = j*256 + tid).
// Exact-fp32 replication of the reference: rn ops, first-index argmax ties.
// One barrier per iteration: packed u64 (dist|~idx) argmax keys, parity-
// double-buffered per-wave partials, centroid re-fetched from global by all
// threads (wave-uniform L2-hit) -> no owner-publish, no second barrier.
__global__ __launch_bounds__(256, 1) void fps_kernel(const float* __restrict__ xyz,
                                                     float* __restrict__ dout) {
  const int b = blockIdx.x;
  const int tid = threadIdx.x;
  const float* xb = xyz + (size_t)b * NN_ * 3;

  float px[32], py[32], pz[32], pd[32];
#pragma unroll
  for (int j = 0; j < 32; ++j) {
    const int p = j * 256 + tid;
    px[j] = xb[p * 3 + 0];
    py[j] = xb[p * 3 + 1];
    pz[j] = xb[p * 3 + 2];
    pd[j] = 1e10f;
  }

  __shared__ unsigned long long s_key[2][4];  // [iteration parity][wave]

  const int lane = tid & 63;
  const int wv = tid >> 6;
  float* outx = dout + (size_t)b * MM_ * 3;

  float cx = xb[0], cy = xb[1], cz = xb[2];

  for (int it = 0; it < MM_; ++it) {
    if (tid == 0) {
      outx[it * 3 + 0] = cx;
      outx[it * 3 + 1] = cy;
      outx[it * 3 + 2] = cz;
    }
    if (it == MM_ - 1) break;

    // distance update + local argmax (strict > keeps smallest j on ties)
    float ld = -1.0f;
    int lj = 0;
#pragma unroll
    for (int j = 0; j < 32; ++j) {
      const float dx = __fsub_rn(px[j], cx);
      const float dy = __fsub_rn(py[j], cy);
      const float dz = __fsub_rn(pz[j], cz);
      const float dist = __fadd_rn(__fadd_rn(__fmul_rn(dx, dx), __fmul_rn(dy, dy)),
                                   __fmul_rn(dz, dz));
      const float nd = fminf(pd[j], dist);
      pd[j] = nd;
      if (nd > ld) { ld = nd; lj = j; }
    }
    // monotone packed key: max dist, tie -> smaller p (p monotone in j)
    unsigned long long key =
        ((unsigned long long)__float_as_uint(ld) << 32) |
        (unsigned int)(8191 - (lj * 256 + tid));
    // wave butterfly argmax on the packed key
#pragma unroll
    for (int mk = 1; mk < 64; mk <<= 1) {
      const unsigned long long ok = __shfl_xor(key, mk, 64);
      key = (ok > key) ? ok : key;
    }
    if (lane == 0) s_key[it & 1][wv] = key;
    __syncthreads();
    // every thread redundantly reduces the 4 per-wave winners
    const unsigned long long k0 = s_key[it & 1][0];
    const unsigned long long k1 = s_key[it & 1][1];
    const unsigned long long k2 = s_key[it & 1][2];
    const unsigned long long k3 = s_key[it & 1][3];
    unsigned long long ka = (k0 > k1) ? k0 : k1;
    const unsigned long long kb = (k2 > k3) ? k2 : k3;
    ka = (ka > kb) ? ka : kb;
    const int win = 8191 - (int)(unsigned int)(ka & 0xFFFFFFFFu);
    // new centroid: exact coords from global (wave-uniform address, L2-hit)
    cx = xb[win * 3 + 0];
    cy = xb[win * 3 + 1];
    cz = xb[win * 3 + 2];
  }
}

// ============================ KNN =============================
// One wave (block of 64) per center. Each lane owns 128 points (p = jj*64+lane).
// Distances in LDS columns + 16 group-minima in regs; 32 extraction rounds of
// lexicographic (d, p) min — reproduces top_k's set with stable tie-break.
// Dot product uses an FMA chain (matches einsum/gemm inner-loop contraction);
// squared norms stay non-FMA sequential (matches elementwise-square+reduce).
__global__ __launch_bounds__(64) void knn_kernel(const float* __restrict__ xyz,
                                                 const float* __restrict__ dout,
                                                 int* __restrict__ knn) {
  __shared__ float dl[128][64];
  const int lane = threadIdx.x;
  const int center = blockIdx.x;
  const int b = center >> 10;
  const int m = center & 1023;
  const float* xb = xyz + (size_t)b * NN_ * 3;
  const float* cp = dout + (size_t)b * MM_ * 3 + m * 3;
  const float cx = cp[0], cy = cp[1], cz = cp[2];
  const float sm = __fadd_rn(__fadd_rn(__fmul_rn(cx, cx), __fmul_rn(cy, cy)),
                             __fmul_rn(cz, cz));

  float gd[16];
  int gj[16];
#pragma unroll
  for (int g = 0; g < 16; ++g) {
#pragma unroll
    for (int t = 0; t < 8; ++t) {
      const int jj = g * 8 + t;
      const int p = jj * 64 + lane;
      const float x = xb[p * 3 + 0];
      const float y = xb[p * 3 + 1];
      const float z = xb[p * 3 + 2];
      const float sn = __fadd_rn(__fadd_rn(__fmul_rn(x, x), __fmul_rn(y, y)),
                                 __fmul_rn(z, z));
      // FMA-chained contraction: fma(z,Z, fma(y,Y, x*X))
      const float dt = __fmaf_rn(cz, z, __fmaf_rn(cy, y, __fmul_rn(cx, x)));
      const float d = __fsub_rn(__fadd_rn(sm, sn), __fmul_rn(2.0f, dt));
      dl[jj][lane] = d;
      if (t == 0) { gd[g] = d; gj[g] = jj; }
      else if (d < gd[g]) { gd[g] = d; gj[g] = jj; }
    }
  }

  int out_p = 0;
  const float INF = __int_as_float(0x7f800000);
  for (int r = 0; r < 32; ++r) {
    // local best among 16 group minima (strict < keeps smallest jj)
    float ldv = gd[0];
    int ljj = gj[0];
#pragma unroll
    for (int g = 1; g < 16; ++g) {
      if (gd[g] < ldv) { ldv = gd[g]; ljj = gj[g]; }
    }
    int lp = ljj * 64 + lane;
#pragma unroll
    for (int mk = 1; mk < 64; mk <<= 1) {
      const float od = __shfl_xor(ldv, mk, 64);
      const int op = __shfl_xor(lp, mk, 64);
      const bool take = (od < ldv) || (od == ldv && op < lp);
      ldv = take ? od : ldv;
      lp = take ? op : lp;
    }
    if (lane == r) out_p = lp;
    // winner lane marks extracted slot and rebuilds that group's min
    const int wl = lp & 63;
    if (lane == wl) {
      const int jjs = lp >> 6;
      const int gs = jjs >> 3;
      dl[jjs][lane] = INF;
      float md = INF;
      int mj = 0;
#pragma unroll
      for (int t = 0; t < 8; ++t) {
        const int jj2 = gs * 8 + t;
        const float v = dl[jj2][lane];
        if (v < md) { md = v; mj = jj2; }
      }
#pragma unroll
      for (int g = 0; g < 16; ++g) {
        if (g == gs) { gd[g] = md; gj[g] = mj; }
      }
    }
  }
  if (lane < 32) knn[center * 32 + lane] = out_p;
}

// ======================= weight transpose =====================
__global__ void prep_kernel(const float* __restrict__ w1, const float* __restrict__ w2,
                            float* __restrict__ w1t, float* __restrict__ w2t) {
  const int t = blockIdx.x * 256 + threadIdx.x;
  if (t < 4096) { const int o = t >> 6, c = t & 63; w1t[c * 64 + o] = w1[t]; }
  if (t < 8192) { const int o = t >> 6, c = t & 63; w2t[c * 128 + o] = w2[t]; }
}

// ===================== layer-1 stats pass =====================
__global__ __launch_bounds__(256) void s1_kernel(const float* __restrict__ xyz,
                                                 const float* __restrict__ dout,
                                                 const int* __restrict__ knn,
                                                 const float* __restrict__ w0,
                                                 const float* __restrict__ b0,
                                                 float* __restrict__ part1) {
  const int tid = threadIdx.x;
  const int r = blockIdx.x * 256 + tid;
  const int cid = r >> 5;
  const int b = cid >> 10;
  const int m = cid & 1023;
  const int idx = knn[r];
  const float* pp = xyz + ((size_t)b * NN_ + idx) * 3;
  const float* cc = dout + ((size_t)b * MM_ + m) * 3;
  const float fx = pp[0] - cc[0];
  const float fy = pp[1] - cc[1];
  const float fz = pp[2] - cc[2];
  float acc[64];
#pragma unroll
  for (int o = 0; o < 64; ++o)
    acc[o] = fmaf(w0[o * 3 + 2], fz, fmaf(w0[o * 3 + 1], fy, fmaf(w0[o * 3 + 0], fx, b0[o])));
  const int lane = tid & 63;
  float* po = part1 + ((size_t)blockIdx.x * 4 + (tid >> 6)) * 128;
#pragma unroll
  for (int o = 0; o < 64; ++o) {
    float s = acc[o];
    float q = acc[o] * acc[o];
#pragma unroll
    for (int mk = 1; mk < 64; mk <<= 1) { s += __shfl_xor(s, mk, 64); q += __shfl_xor(q, mk, 64); }
    if (lane == 0) { po[o] = s; po[64 + o] = q; }
  }
}

// ============ BN-fold reduce: partials -> scale/shift ==========
__global__ __launch_bounds__(256) void rstat_kernel(const float* __restrict__ part, int C,
                                                    const float* __restrict__ g,
                                                    const float* __restrict__ be,
                                                    float* __restrict__ sc,
                                                    float* __restrict__ sh) {
  const int c = blockIdx.x;
  const int tid = threadIdx.x;
  float S = 0.0f, Q = 0.0f;
  for (int i = tid; i < 4096; i += 256) {
    S += part[(size_t)i * 2 * C + c];
    Q += part[(size_t)i * 2 * C + C + c];
  }
  const int lane = tid & 63;
#pragma unroll
  for (int mk = 1; mk < 64; mk <<= 1) { S += __shfl_xor(S, mk, 64); Q += __shfl_xor(Q, mk, 64); }
  __shared__ float rs[4], rq[4];
  if (lane == 0) { rs[tid >> 6] = S; rq[tid >> 6] = Q; }
  __syncthreads();
  if (tid == 0) {
    S = rs[0] + rs[1] + rs[2] + rs[3];
    Q = rq[0] + rq[1] + rq[2] + rq[3];
    const float mean = S * (1.0f / 262144.0f);
    const float var = fmaf(-mean, mean, Q * (1.0f / 262144.0f));
    const float s = g[c] * rsqrtf(var + 1e-5f);
    sc[c] = s;
    sh[c] = fmaf(-mean, s, be[c]);
  }
}

// ============ recompute chain: STAGE 2 = stats2, 3 = stats3, 4 = final ============
template <int STAGE>
__global__ __launch_bounds__(256) void chain_kernel(
    const float* __restrict__ xyz, const float* __restrict__ dout,
    const int* __restrict__ knn,
    const float* __restrict__ w0, const float* __restrict__ b0,
    const float* __restrict__ w1t, const float* __restrict__ b1,
    const float* __restrict__ w2t, const float* __restrict__ b2,
    const float* __restrict__ sc1, const float* __restrict__ sh1,
    const float* __restrict__ sc2, const float* __restrict__ sh2,
    const float* __restrict__ sc3, const float* __restrict__ sh3,
    float* __restrict__ part, float* __restrict__ outp) {
  __shared__ float f[64 * 256];  // activations, column layout [c][tid]
  const int tid = threadIdx.x;
  const int r = blockIdx.x * 256 + tid;
  const int cid = r >> 5;
  const int b = cid >> 10;
  const int m = cid & 1023;
  const int idx = knn[r];
  const float* pp = xyz + ((size_t)b * NN_ + idx) * 3;
  const float* cc = dout + ((size_t)b * MM_ + m) * 3;
  const float fx = pp[0] - cc[0];
  const float fy = pp[1] - cc[1];
  const float fz = pp[2] - cc[2];
  float acc[64];
#pragma unroll
  for (int o = 0; o < 64; ++o)
    acc[o] = fmaf(w0[o * 3 + 2], fz, fmaf(w0[o * 3 + 1], fy, fmaf(w0[o * 3 + 0], fx, b0[o])));
  // BN1 + ReLU -> LDS (own column only; no barrier needed)
#pragma unroll
  for (int o = 0; o < 64; ++o)
    f[o * 256 + tid] = fmaxf(fmaf(acc[o], sc1[o], sh1[o]), 0.0f);
  // conv2 (output-stationary, uniform weight loads)
  float a2[64];
#pragma unroll
  for (int o = 0; o < 64; ++o) a2[o] = b1[o];
#pragma unroll 4
  for (int c = 0; c < 64; ++c) {
    const float x = f[c * 256 + tid];
#pragma unroll
    for (int o = 0; o < 64; ++o) a2[o] = fmaf(w1t[c * 64 + o], x, a2[o]);
  }
  const int lane = tid & 63;
  if constexpr (STAGE == 2) {
    float* po = part + ((size_t)blockIdx.x * 4 + (tid >> 6)) * 128;
#pragma unroll
    for (int o = 0; o < 64; ++o) {
      float s = a2[o], q = a2[o] * a2[o];
#pragma unroll
      for (int mk = 1; mk < 64; mk <<= 1) { s += __shfl_xor(s, mk, 64); q += __shfl_xor(q, mk, 64); }
      if (lane == 0) { po[o] = s; po[64 + o] = q; }
    }
    return;
  }
  // BN2 + ReLU -> LDS (overwrite own column)
#pragma unroll
  for (int o = 0; o < 64; ++o)
    f[o * 256 + tid] = fmaxf(fmaf(a2[o], sc2[o], sh2[o]), 0.0f);
#pragma unroll
  for (int h = 0; h < 2; ++h) {
    float a3[64];
#pragma unroll
    for (int o = 0; o < 64; ++o) a3[o] = b2[h * 64 + o];
#pragma unroll 4
    for (int c = 0; c < 64; ++c) {
      const float x = f[c * 256 + tid];
#pragma unroll
      for (int o = 0; o < 64; ++o) a3[o] = fmaf(w2t[c * 128 + h * 64 + o], x, a3[o]);
    }
    if constexpr (STAGE == 3) {
      float* po = part + ((size_t)blockIdx.x * 4 + (tid >> 6)) * 256;
#pragma unroll
      for (int o = 0; o < 64; ++o) {
        float s = a3[o], q = a3[o] * a3[o];
#pragma unroll
        for (int mk = 1; mk < 64; mk <<= 1) { s += __shfl_xor(s, mk, 64); q += __shfl_xor(q, mk, 64); }
        if (lane == 0) { po[h * 64 + o] = s; po[128 + h * 64 + o] = q; }
      }
    } else {
      // BN3 + ReLU + max over k (32 lanes) + transposed store
#pragma unroll
      for (int o = 0; o < 64; ++o) {
        float v = fmaxf(fmaf(a3[o], sc3[h * 64 + o], sh3[h * 64 + o]), 0.0f);
#pragma unroll
        for (int mk = 1; mk < 32; mk <<= 1) v = fmaxf(v, __shfl_xor(v, mk, 64));
        if ((lane & 31) == 0)
          outp[24576 + (size_t)b * 131072 + (size_t)(h * 64 + o) * 1024 + m] = v;
      }
    }
  }
}

// ============================ launch =============================
extern "C" void kernel_launch(void* const* d_in, const int* in_sizes, int n_in,
                              void* d_out, int out_size, void* d_ws, size_t ws_size,
                              hipStream_t stream) {
  const float* xyz = (const float*)d_in[0];
  const float* w0 = (const float*)d_in[1];
  const float* b0 = (const float*)d_in[2];
  const float* g0 = (const float*)d_in[3];
  const float* be0 = (const float*)d_in[4];
  const float* w1 = (const float*)d_in[5];
  const float* b1 = (const float*)d_in[6];
  const float* g1 = (const float*)d_in[7];
  const float* be1 = (const float*)d_in[8];
  const float* w2 = (const float*)d_in[9];
  const float* b2 = (const float*)d_in[10];
  const float* g2 = (const float*)d_in[11];
  const float* be2 = (const float*)d_in[12];
  float* out = (float*)d_out;
  char* ws = (char*)d_ws;

  // ws layout (~9.5 MB total):
  int* knn = (int*)ws;                                   // [8192][32] ints
  float* part1 = (float*)(ws + (size_t)1 * (1 << 20));   // [4096][128]
  float* part2 = (float*)(ws + (size_t)3 * (1 << 20));   // [4096][128]
  float* part3 = (float*)(ws + (size_t)5 * (1 << 20));   // [4096][256]
  float* sc1 = (float*)(ws + (size_t)9 * (1 << 20));
  float* sh1 = sc1 + 64;
  float* sc2 = sh1 + 64;
  float* sh2 = sc2 + 64;
  float* sc3 = sh2 + 64;
  float* sh3 = sc3 + 128;
  float* w1t = sh3 + 128;
  float* w2t = w1t + 4096;

  fps_kernel<<<8, 256, 0, stream>>>(xyz, out);
  knn_kernel<<<8192, 64, 0, stream>>>(xyz, out, knn);
  prep_kernel<<<32, 256, 0, stream>>>(w1, w2, w1t, w2t);
  s1_kernel<<<1024, 256, 0, stream>>>(xyz, out, knn, w0, b0, part1);
  rstat_kernel<<<64, 256, 0, stream>>>(part1, 64, g0, be0, sc1, sh1);
  chain_kernel<2><<<1024, 256, 0, stream>>>(xyz, out, knn, w0, b0, w1t, b1, w2t, b2,
                                            sc1, sh1, sc2, sh2, sc3, sh3, part2, out);
  rstat_kernel<<<64, 256, 0, stream>>>(part2, 64, g1, be1, sc2, sh2);
  chain_kernel<3><<<1024, 256, 0, stream>>>(xyz, out, knn, w0, b0, w1t, b1, w2t, b2,
                                            sc1, sh1, sc2, sh2, sc3, sh3, part3, out);
  rstat_kernel<<<128, 256, 0, stream>>>(part3, 128, g2, be2, sc3, sh3);
  chain_kernel<4><<<1024, 256, 0, stream>>>(xyz, out, knn, w0, b0, w1t, b1, w2t, b2,
                                            sc1, sh1, sc2, sh2, sc3, sh3, part3, out);
}